// Round 1
// baseline (42.881 us; speedup 1.0000x reference)
//
#include <hip/hip_runtime.h>
#include <stdint.h>

typedef float  f32x4  __attribute__((ext_vector_type(4)));
typedef __bf16 bf16x8 __attribute__((ext_vector_type(8)));

#define N_ROWS 131072
#define K_CODES 1024
// ws layout (bytes):
//  [0, 131072)        swizzled bf16 codebook (row j: 128B, 16B chunk q at (q*16 ^ ((j&7)<<4)))
//  [131072, 135168)   e2 fp32[1024]
//  [135168, 136192)   per-block loss partials fp32[256]
#define WS_E2_OFF   131072
#define WS_PART_OFF 135168

// smem layout:
#define SM_E2_OFF   131072
#define SM_IDX_OFF  135168   // int[512]
#define SM_LOSS_OFF 137216   // float[8]
#define SM_BYTES    137248

__global__ __launch_bounds__(256) void prep_kernel(const float* __restrict__ cb,
                                                   uint8_t* __restrict__ ws) {
  int j = blockIdx.x * 256 + threadIdx.x;   // 0..1023, one codebook row per thread
  if (j >= K_CODES) return;
  const float* row = cb + (size_t)j * 64;
  float e2 = 0.f;
  const uint32_t sw = (uint32_t)((j & 7) << 4);
  uint8_t* out = ws + (size_t)j * 128;
#pragma unroll
  for (int q = 0; q < 8; ++q) {
    uint32_t d[4];
#pragma unroll
    for (int p = 0; p < 4; ++p) {
      float a = row[q * 8 + p * 2];
      float b = row[q * 8 + p * 2 + 1];
      e2 = fmaf(a, a, e2);
      e2 = fmaf(b, b, e2);
      uint32_t lo = (uint32_t)__builtin_bit_cast(uint16_t, (__bf16)a);
      uint32_t hi = (uint32_t)__builtin_bit_cast(uint16_t, (__bf16)b);
      d[p] = lo | (hi << 16);
    }
    uint32_t off = ((uint32_t)(q * 16)) ^ sw;   // pre-swizzled so LDS copy is linear
    *(uint4*)(out + off) = make_uint4(d[0], d[1], d[2], d[3]);
  }
  *(float*)(ws + WS_E2_OFF + (size_t)j * 4) = e2;
}

__global__ __launch_bounds__(512) void vq_main(const float* __restrict__ x,
                                               const float* __restrict__ cb,
                                               float* __restrict__ out,
                                               const uint8_t* __restrict__ ws,
                                               float* __restrict__ parts) {
  __shared__ __align__(16) uint8_t smem[SM_BYTES];

  // stage swizzled bf16 codebook + e2 (135168 B) into LDS
  {
    const uint4* src = (const uint4*)ws;
    uint4* dst = (uint4*)smem;
    for (int i = threadIdx.x; i < 8448; i += 512) dst[i] = src[i];
  }
  __syncthreads();

  const int lane = threadIdx.x & 63;
  const int w    = threadIdx.x >> 6;
  const int lr   = lane & 15;     // A row / B code within 16-tile
  const int lg   = lane >> 4;     // k-chunk group 0..3
  const int rowbase = blockIdx.x * 512 + w * 64;

  // A fragments: 4 row-tiles x 2 k-chunks, fp32 -> bf16 in-register
  bf16x8 afrag[4][2];
#pragma unroll
  for (int rt = 0; rt < 4; ++rt) {
    const float* rp = x + (size_t)(rowbase + rt * 16 + lr) * 64 + lg * 8;
#pragma unroll
    for (int c = 0; c < 2; ++c) {
      f32x4 f0 = *(const f32x4*)(rp + c * 32);
      f32x4 f1 = *(const f32x4*)(rp + c * 32 + 4);
      bf16x8 a;
#pragma unroll
      for (int e = 0; e < 4; ++e) { a[e] = (__bf16)f0[e]; a[e + 4] = (__bf16)f1[e]; }
      afrag[rt][c] = a;
    }
  }

  // running packed min-keys: (d & ~1023) | code_idx ; fminf selects min distance
  float kmin[4][4];
#pragma unroll
  for (int rt = 0; rt < 4; ++rt)
#pragma unroll
    for (int r = 0; r < 4; ++r) kmin[rt][r] = __builtin_bit_cast(float, 0x7F800000u);

  const float* e2p = (const float*)(smem + SM_E2_OFF);
  uint32_t vj = (uint32_t)lr;

#pragma unroll 2
  for (int t = 0; t < 64; ++t) {
    const int jrow = (t << 4) + lr;
    const uint32_t rb = (uint32_t)jrow * 128;
    const uint32_t sw = (uint32_t)((jrow & 7) << 4);
    bf16x8 b0 = *(const bf16x8*)(smem + rb + (((uint32_t)(lg * 16)) ^ sw));
    bf16x8 b1 = *(const bf16x8*)(smem + rb + (((uint32_t)(64 + lg * 16)) ^ sw));
    float e2j = e2p[jrow];
#pragma unroll
    for (int rt = 0; rt < 4; ++rt) {
      f32x4 acc = {0.f, 0.f, 0.f, 0.f};
      acc = __builtin_amdgcn_mfma_f32_16x16x32_bf16(afrag[rt][0], b0, acc, 0, 0, 0);
      acc = __builtin_amdgcn_mfma_f32_16x16x32_bf16(afrag[rt][1], b1, acc, 0, 0, 0);
#pragma unroll
      for (int r = 0; r < 4; ++r) {
        float d = fmaf(acc[r], -2.0f, e2j);
        uint32_t key = (__builtin_bit_cast(uint32_t, d) & 0xFFFFFC00u) | vj;
        kmin[rt][r] = fminf(kmin[rt][r], __builtin_bit_cast(float, key));
      }
    }
    vj += 16;
  }

  // argmin across the 16 code-slots (lr dimension) per 16-lane group
#pragma unroll
  for (int rt = 0; rt < 4; ++rt)
#pragma unroll
    for (int r = 0; r < 4; ++r) {
      float v = kmin[rt][r];
#pragma unroll
      for (int m = 1; m < 16; m <<= 1) v = fminf(v, __shfl_xor(v, m, 64));
      kmin[rt][r] = v;
    }

  // stage per-row indices to LDS (wave-local)
  int* sh_idx = (int*)(smem + SM_IDX_OFF) + w * 64;
  if (lr == 0) {
#pragma unroll
    for (int rt = 0; rt < 4; ++rt)
#pragma unroll
      for (int r = 0; r < 4; ++r)
        sh_idx[rt * 16 + lg * 4 + r] =
            (int)(__builtin_bit_cast(uint32_t, kmin[rt][r]) & 1023u);
  }
  asm volatile("s_waitcnt lgkmcnt(0)" ::: "memory");

  // gather + write quantized + loss (coalesced float4: 4 rows/iter, 16 lanes/row)
  float lsum = 0.f;
#pragma unroll 4
  for (int it = 0; it < 16; ++it) {
    int rloc = it * 4 + lg;
    int row = rowbase + rloc;
    int idx = sh_idx[rloc];
    f32x4 q  = *(const f32x4*)(cb + (size_t)idx * 64 + lr * 4);
    f32x4 xv = *(const f32x4*)(x + (size_t)row * 64 + lr * 4);
    *(f32x4*)(out + (size_t)row * 64 + lr * 4) = q;
    f32x4 df = q - xv;
    lsum += df[0] * df[0] + df[1] * df[1] + df[2] * df[2] + df[3] * df[3];
  }

#pragma unroll
  for (int m = 1; m < 64; m <<= 1) lsum += __shfl_xor(lsum, m, 64);
  float* sh_loss = (float*)(smem + SM_LOSS_OFF);
  if (lane == 0) sh_loss[w] = lsum;
  __syncthreads();
  if (threadIdx.x == 0) {
    float s = 0.f;
    for (int i = 0; i < 8; ++i) s += sh_loss[i];
    parts[blockIdx.x] = s;
  }
}

__global__ __launch_bounds__(256) void finish_kernel(const float* __restrict__ parts,
                                                     float* __restrict__ loss_out) {
  __shared__ float sh[4];
  float v = parts[threadIdx.x];
#pragma unroll
  for (int m = 1; m < 64; m <<= 1) v += __shfl_xor(v, m, 64);
  int w = threadIdx.x >> 6, lane = threadIdx.x & 63;
  if (lane == 0) sh[w] = v;
  __syncthreads();
  if (threadIdx.x == 0) {
    float s = sh[0] + sh[1] + sh[2] + sh[3];
    loss_out[0] = 1.25f * (s / 8388608.0f);
  }
}

extern "C" void kernel_launch(void* const* d_in, const int* in_sizes, int n_in,
                              void* d_out, int out_size, void* d_ws, size_t ws_size,
                              hipStream_t stream) {
  const float* x  = (const float*)d_in[0];
  const float* cb = (const float*)d_in[1];
  float* out = (float*)d_out;
  uint8_t* ws = (uint8_t*)d_ws;
  float* parts = (float*)(ws + WS_PART_OFF);

  hipLaunchKernelGGL(prep_kernel, dim3(4), dim3(256), 0, stream, cb, ws);
  hipLaunchKernelGGL(vq_main, dim3(256), dim3(512), 0, stream, x, cb, out, ws, parts);
  hipLaunchKernelGGL(finish_kernel, dim3(1), dim3(256), 0, stream, parts, out + 8388608);
}

// Round 2
// 28.783 us; speedup vs baseline: 1.4898x; 1.4898x over previous
//
#include <hip/hip_runtime.h>
#include <stdint.h>

typedef float    f32x4 __attribute__((ext_vector_type(4)));
typedef uint32_t u32x4 __attribute__((ext_vector_type(4)));

// ws layout (bytes):
//  [0, 65536)       fp8 codebook, t-grouped lane order:
//                   tile t (16 codes), lane l=(lg*16+lr): 16B at t*1024 + l*16 =
//                   { fp8(1024*e[code t*16+lr][lg*8 .. +8)), fp8(1024*e[..][32+lg*8 .. +8)) }
//  [65536, 69632)   e2 fp32[1024]  (unscaled, exact)
//  [69632, 71680)   per-block loss partials fp32[512]
#define WS_E2   65536
#define WS_PART 69632

// LDS layout: mirrors ws [0,69632) linearly, + idx + loss scratch
#define SM_E2   65536
#define SM_IDX  69632   // 8 waves * 32 int
#define SM_LOSS 70656   // 8 floats
#define SM_SZ   70688

__device__ __forceinline__ uint32_t pk4(float a, float b, float c, float d) {
  int v = 0;
  v = __builtin_amdgcn_cvt_pk_fp8_f32(a, b, v, false);
  v = __builtin_amdgcn_cvt_pk_fp8_f32(c, d, v, true);
  return (uint32_t)v;
}

__device__ __forceinline__ float d4(f32x4 v) {
  return v[0]*v[0] + v[1]*v[1] + v[2]*v[2] + v[3]*v[3];
}

__global__ __launch_bounds__(256) void prep_kernel(const float* __restrict__ cb,
                                                   uint8_t* __restrict__ ws) {
  int j = blockIdx.x * 256 + threadIdx.x;   // code row 0..1023
  const float* row = cb + (size_t)j * 64;
  const int t = j >> 4, lr = j & 15;
  float e2 = 0.f;
#pragma unroll
  for (int lg = 0; lg < 4; ++lg) {
    f32x4 a0 = *(const f32x4*)(row + lg * 8);
    f32x4 a1 = *(const f32x4*)(row + lg * 8 + 4);
    f32x4 b0 = *(const f32x4*)(row + 32 + lg * 8);
    f32x4 b1 = *(const f32x4*)(row + 32 + lg * 8 + 4);
    e2 += d4(a0) + d4(a1) + d4(b0) + d4(b1);
    u32x4 o;
    o[0] = pk4(1024.f*a0[0], 1024.f*a0[1], 1024.f*a0[2], 1024.f*a0[3]);
    o[1] = pk4(1024.f*a1[0], 1024.f*a1[1], 1024.f*a1[2], 1024.f*a1[3]);
    o[2] = pk4(1024.f*b0[0], 1024.f*b0[1], 1024.f*b0[2], 1024.f*b0[3]);
    o[3] = pk4(1024.f*b1[0], 1024.f*b1[1], 1024.f*b1[2], 1024.f*b1[3]);
    *(u32x4*)(ws + (size_t)t * 1024 + (size_t)(lg * 16 + lr) * 16) = o;
  }
  *(float*)(ws + WS_E2 + (size_t)j * 4) = e2;
}

__global__ __launch_bounds__(512, 4) void vq_main(const float* __restrict__ x,
                                                  const float* __restrict__ cb,
                                                  float* __restrict__ out,
                                                  const uint8_t* __restrict__ ws,
                                                  float* __restrict__ parts) {
  __shared__ __align__(16) uint8_t smem[SM_SZ];
  const int tid = threadIdx.x, lane = tid & 63, w = tid >> 6;
  const int lr = lane & 15, lg = lane >> 4;
  const int rowbase = blockIdx.x * 256 + w * 32;

  // ---- A: load x rows (nontemporal), fp32 x^2 partial, pack fp8 frags ----
  float x2p = 0.f;
  long afrag[2][2];
#pragma unroll
  for (int rt = 0; rt < 2; ++rt) {
    const float* rp = x + (size_t)(rowbase + rt * 16 + lr) * 64 + lg * 8;
    f32x4 a0 = __builtin_nontemporal_load((const f32x4*)rp);
    f32x4 a1 = __builtin_nontemporal_load((const f32x4*)(rp + 4));
    f32x4 b0 = __builtin_nontemporal_load((const f32x4*)(rp + 32));
    f32x4 b1 = __builtin_nontemporal_load((const f32x4*)(rp + 36));
    x2p += d4(a0) + d4(a1) + d4(b0) + d4(b1);
    uint32_t w0 = pk4(a0[0], a0[1], a0[2], a0[3]);
    uint32_t w1 = pk4(a1[0], a1[1], a1[2], a1[3]);
    uint32_t w2 = pk4(b0[0], b0[1], b0[2], b0[3]);
    uint32_t w3 = pk4(b1[0], b1[1], b1[2], b1[3]);
    afrag[rt][0] = (long)(((uint64_t)w1 << 32) | w0);
    afrag[rt][1] = (long)(((uint64_t)w3 << 32) | w2);
  }

  // ---- stage fp8 codebook (64KB) + e2 (4KB) via async global->LDS ----
  {
    const uint8_t* gsrc = ws + (size_t)w * 8192 + (size_t)lane * 16;
    uint8_t* ldst = smem + w * 8192;
#pragma unroll
    for (int i = 0; i < 8; ++i)
      __builtin_amdgcn_global_load_lds(
          (const __attribute__((address_space(1))) uint32_t*)(gsrc + i * 1024),
          (__attribute__((address_space(3))) uint32_t*)(ldst + i * 1024), 16, 0, 0);
    if (w < 4)
      __builtin_amdgcn_global_load_lds(
          (const __attribute__((address_space(1))) uint32_t*)(ws + WS_E2 + (size_t)w * 1024 + (size_t)lane * 16),
          (__attribute__((address_space(3))) uint32_t*)(smem + SM_E2 + w * 1024), 16, 0, 0);
  }
  __syncthreads();

  // ---- argmax over acc = 1024 * x.e ; pack code idx into low 10 mantissa bits ----
  float kmax[2][4];
#pragma unroll
  for (int rt = 0; rt < 2; ++rt)
#pragma unroll
    for (int r = 0; r < 4; ++r) kmax[rt][r] = __builtin_bit_cast(float, 0xFF800000u);

  const uint8_t* bptr = smem + lane * 16;
  uint32_t jcur = (uint32_t)lr;
#pragma unroll 4
  for (int t = 0; t < 64; ++t) {
    u32x4 b = *(const u32x4*)(bptr + t * 1024);
    long bf0 = (long)(((uint64_t)b[1] << 32) | b[0]);
    long bf1 = (long)(((uint64_t)b[3] << 32) | b[2]);
#pragma unroll
    for (int rt = 0; rt < 2; ++rt) {
      f32x4 acc = {0.f, 0.f, 0.f, 0.f};
      acc = __builtin_amdgcn_mfma_f32_16x16x32_fp8_fp8(afrag[rt][0], bf0, acc, 0, 0, 0);
      acc = __builtin_amdgcn_mfma_f32_16x16x32_fp8_fp8(afrag[rt][1], bf1, acc, 0, 0, 0);
#pragma unroll
      for (int r = 0; r < 4; ++r) {
        uint32_t key = (__builtin_bit_cast(uint32_t, acc[r]) & 0xFFFFFC00u) | jcur;
        kmax[rt][r] = fmaxf(kmax[rt][r], __builtin_bit_cast(float, key));
      }
    }
    jcur += 16;
  }

  // reduce over the 16 code-slot lanes
#pragma unroll
  for (int rt = 0; rt < 2; ++rt)
#pragma unroll
    for (int r = 0; r < 4; ++r) {
      float v = kmax[rt][r];
#pragma unroll
      for (int m = 1; m < 16; m <<= 1) v = fmaxf(v, __shfl_xor(v, m, 64));
      kmax[rt][r] = v;
    }

  // loss partial: sum_rows(x2 - dot/512), dot' replicated over 16 lanes -> /8192
  float dsum = 0.f;
#pragma unroll
  for (int rt = 0; rt < 2; ++rt)
#pragma unroll
    for (int r = 0; r < 4; ++r)
      dsum += __builtin_bit_cast(float, __builtin_bit_cast(uint32_t, kmax[rt][r]) & 0xFFFFFC00u);
  float lsum = x2p - dsum * (1.0f / 8192.0f);

  // ---- exchange per-row indices (wave-local) ----
  int* sh_idx = (int*)(smem + SM_IDX) + w * 32;
  if (lr == 0) {
#pragma unroll
    for (int rt = 0; rt < 2; ++rt)
#pragma unroll
      for (int r = 0; r < 4; ++r)
        sh_idx[rt * 16 + lg * 4 + r] =
            (int)(__builtin_bit_cast(uint32_t, kmax[rt][r]) & 1023u);
  }
  asm volatile("s_waitcnt lgkmcnt(0)" ::: "memory");

  // ---- gather fp32 codebook rows + write out + e2 loss term ----
  const float* e2f = (const float*)(smem + SM_E2);
#pragma unroll
  for (int it = 0; it < 8; ++it) {
    int rloc = it * 4 + lg;
    int idx = sh_idx[rloc];
    f32x4 q = *(const f32x4*)(cb + (size_t)idx * 64 + lr * 4);
    __builtin_nontemporal_store(q, (f32x4*)(out + (size_t)(rowbase + rloc) * 64 + lr * 4));
    if (lr == 0) lsum += e2f[idx];
  }

#pragma unroll
  for (int m = 1; m < 64; m <<= 1) lsum += __shfl_xor(lsum, m, 64);
  float* shl = (float*)(smem + SM_LOSS);
  if (lane == 0) shl[w] = lsum;
  __syncthreads();
  if (tid == 0) {
    float s = 0.f;
#pragma unroll
    for (int i = 0; i < 8; ++i) s += shl[i];
    parts[blockIdx.x] = s;
  }
}

__global__ __launch_bounds__(512) void finish_kernel(const float* __restrict__ parts,
                                                     float* __restrict__ loss_out) {
  __shared__ float sh[8];
  float v = parts[threadIdx.x];
#pragma unroll
  for (int m = 1; m < 64; m <<= 1) v += __shfl_xor(v, m, 64);
  int w = threadIdx.x >> 6, lane = threadIdx.x & 63;
  if (lane == 0) sh[w] = v;
  __syncthreads();
  if (threadIdx.x == 0) {
    float s = 0.f;
#pragma unroll
    for (int i = 0; i < 8; ++i) s += sh[i];
    loss_out[0] = 1.25f * (s / 8388608.0f);
  }
}

extern "C" void kernel_launch(void* const* d_in, const int* in_sizes, int n_in,
                              void* d_out, int out_size, void* d_ws, size_t ws_size,
                              hipStream_t stream) {
  const float* x  = (const float*)d_in[0];
  const float* cb = (const float*)d_in[1];
  float* out = (float*)d_out;
  uint8_t* ws = (uint8_t*)d_ws;
  float* parts = (float*)(ws + WS_PART);

  hipLaunchKernelGGL(prep_kernel, dim3(4), dim3(256), 0, stream, cb, ws);
  hipLaunchKernelGGL(vq_main, dim3(512), dim3(512), 0, stream, x, cb, out, ws, parts);
  hipLaunchKernelGGL(finish_kernel, dim3(1), dim3(512), 0, stream, parts, out + 8388608);
}